// Round 15
// baseline (1146.547 us; speedup 1.0000x reference)
//
#include <hip/hip_runtime.h>
#include <hip/hip_fp16.h>
#include <hip/hip_cooperative_groups.h>

// GCN 3-layer fused pipeline for MI355X.
// N=50000, E=800000, F=128. edge_index int32 [row[0..E), col[0..E)].
// Established: random-gather = 64B-lines-touched ceiling (fp16 rows, ~30us);
//   MFMA GEMM <20us; R14 accounting: kernels ~150us vs total 280us ->
//   ~130us is inter-dispatch overhead across 11 launches.
// R15: collapse to 2 cooperative kernels with grid.sync() phase barriers:
//   k_csr  = zero+Wconvert | count | scan | fill
//   k_mega = gemm1 | agg1 | gemm2 | agg2+fused-gemv3 | agg3
//   (gemv3 fused into agg2: t2 stays in registers; saves dispatch + 50MB traffic)

namespace cg = cooperative_groups;

typedef _Float16 half8 __attribute__((ext_vector_type(8)));
typedef float f32x4 __attribute__((ext_vector_type(4)));

// ---------------- CSR build (cooperative, 1024 x 256) ----------------
__global__ __launch_bounds__(256, 4) void k_csr(
    const int* __restrict__ ei, int* __restrict__ cnt, int* __restrict__ offs,
    int* __restrict__ cursor, float* __restrict__ dinv, int* __restrict__ gsum,
    int* __restrict__ csr, const float* __restrict__ W1, const float* __restrict__ W2,
    _Float16* __restrict__ WtA, _Float16* __restrict__ WtB, int E, int N, int NB) {
  cg::grid_group grid = cg::this_grid();
  __shared__ int s[256];
  int tid = threadIdx.x, b = blockIdx.x;
  int gid = b * 256 + tid;
  int gsz = gridDim.x * 256;

  // P0: zero cnt + convert W1/W2 -> fp16 transposed+swizzled Wt[col][k]
  for (int i = gid; i < N; i += gsz) cnt[i] = 0;
  if (gid < 32768) {
    int which = gid >> 14, e = gid & 16383;
    int c = e >> 7, k = e & 127;
    const float* Wsrc = which ? W2 : W1;
    _Float16 h = (_Float16)Wsrc[k * 128 + c];
    char* dst = (char*)(which ? WtB : WtA);
    *(_Float16*)(dst + c * 256 + ((k * 2) ^ ((c & 7) << 4))) = h;
  }
  grid.sync();

  // P1: degree count
  for (int e = gid; e < E; e += gsz) {
    unsigned c = (unsigned)ei[E + e];
    if (c < (unsigned)N) atomicAdd(&cnt[c], 1);
  }
  grid.sync();

  // P2: block-local scan + dinv (first NB blocks only)
  int lexcl = 0;
  if (b < NB) {
    int i = gid;
    int v = (i < N) ? cnt[i] : 0;
    if (i < N) dinv[i] = rsqrtf((float)(v + 1));  // +1 self loop
    s[tid] = v;
    __syncthreads();
    for (int d = 1; d < 256; d <<= 1) {
      int t = (tid >= d) ? s[tid - d] : 0;
      __syncthreads();
      s[tid] += t;
      __syncthreads();
    }
    lexcl = s[tid] - v;
    if (tid == 255) gsum[b] = s[255];
  }
  grid.sync();

  // P3: cross-block offsets -> offs/cursor
  if (b < NB) {
    s[tid] = (tid < b) ? gsum[tid] : 0;
    __syncthreads();
    for (int d = 128; d > 0; d >>= 1) {
      if (tid < d) s[tid] += s[tid + d];
      __syncthreads();
    }
    int o = s[0] + lexcl;
    int i = gid;
    if (i < N) {
      offs[i] = o;
      cursor[i] = o;
    }
    if (i == 0) offs[N] = E;
  }
  grid.sync();

  // P4: XCD-sliced fill (slice = blockIdx&7 -> XCD, dest-range local)
  {
    int sl = b & 7;
    unsigned lo = (unsigned)((sl * (long long)N) >> 3);
    unsigned hi = (unsigned)(((sl + 1) * (long long)N) >> 3);
    int stride = (gridDim.x >> 3) * 256;
    for (int e = (b >> 3) * 256 + tid; e < E; e += stride) {
      unsigned c = (unsigned)ei[E + e];
      if (c >= lo && c < hi) {
        unsigned r = (unsigned)ei[e];
        if (r < (unsigned)N) {
          int p = atomicAdd(&cursor[c], 1);
          csr[p] = (int)r;
        }
      }
    }
  }
}

// ---------------- mega compute kernel helpers ----------------

// MFMA GEMM phase: G[row][col] = fp16(dinv[row] * sum_k X[row][k]*W[k][col]).
// Layouts (guide-verified): A row=l&15,k=(l>>4)*8+j; B k=(l>>4)*8+j,col=l&15;
// C/D col=l&15,row=(l>>4)*4+reg. Wt pre-swizzled byte ^ (col&7)<<4.
__device__ inline void gemm_phase(const float* __restrict__ X, const _Float16* __restrict__ Wt,
                                  const float* __restrict__ dinv, __half* __restrict__ G,
                                  _Float16* Wl, int N, int nT) {
  if ((int)blockIdx.x >= nT) return;
  int tid = threadIdx.x;
  int w = tid >> 6, l = tid & 63;
  int cl = l & 15, kg = l >> 4;
  int row0 = blockIdx.x * 64 + w * 16;

  for (int i = tid; i < 2048; i += 256)
    ((uint4*)Wl)[i] = ((const uint4*)Wt)[i];
  __syncthreads();

  int ra = row0 + cl;
  size_t xb = (size_t)((ra < N) ? ra : (N - 1)) * 32;
  const float4* __restrict__ X4 = (const float4*)X;
  half8 a[4];
#pragma unroll
  for (int k0 = 0; k0 < 4; k0++) {
    float4 f0 = X4[xb + k0 * 8 + kg * 2];
    float4 f1 = X4[xb + k0 * 8 + kg * 2 + 1];
    half8 h;
    h[0] = (_Float16)f0.x; h[1] = (_Float16)f0.y;
    h[2] = (_Float16)f0.z; h[3] = (_Float16)f0.w;
    h[4] = (_Float16)f1.x; h[5] = (_Float16)f1.y;
    h[6] = (_Float16)f1.z; h[7] = (_Float16)f1.w;
    a[k0] = h;
  }

  int rowc = row0 + kg * 4;
  float dv[4];
#pragma unroll
  for (int r = 0; r < 4; r++) {
    int rc = rowc + r;
    dv[r] = dinv[(rc < N) ? rc : (N - 1)];
  }

#pragma unroll
  for (int g = 0; g < 8; g++) {
    int col = g * 16 + cl;
    int swz = (col & 7) << 4;
    f32x4 acc = {0.f, 0.f, 0.f, 0.f};
#pragma unroll
    for (int k0 = 0; k0 < 4; k0++) {
      int byteoff = col * 256 + ((k0 * 64 + kg * 16) ^ swz);
      half8 bfrag = *(const half8*)((const char*)Wl + byteoff);
      acc = __builtin_amdgcn_mfma_f32_16x16x32_f16(a[k0], bfrag, acc, 0, 0, 0);
    }
#pragma unroll
    for (int r = 0; r < 4; r++) {
      int rc = rowc + r;
      if (rc < N) G[(size_t)rc * 128 + g * 16 + cl] = __float2half_rn(dv[r] * acc[r]);
    }
  }
}

__device__ inline float4 cvt4(uint2 u) {
  __half2 a = *reinterpret_cast<__half2*>(&u.x);
  __half2 b = *reinterpret_cast<__half2*>(&u.y);
  float2 fa = __half22float2(a);
  float2 fb = __half22float2(b);
  return make_float4(fa.x, fa.y, fb.x, fb.y);
}

// Aggregate + activate. FUSE_GEMV=0: tOut[v] = relu(dinv*(agg)+bias) (f32 rows).
// FUSE_GEMV=1: g3[v] = dinv[v] * dot(relu(dinv*agg+bias), W3)  (t2 in registers).
template <int FUSE_GEMV>
__device__ inline void agg_phase(const __half* __restrict__ g, const int* __restrict__ offs,
                                 const int* __restrict__ csr, const float* __restrict__ dinv,
                                 const float* __restrict__ bias, const float* __restrict__ W3,
                                 float* __restrict__ tOut, float* __restrict__ g3, int N, int nG) {
  int wid = threadIdx.x >> 6;
  int lane = threadIdx.x & 63;
  int hf = lane >> 5;
  int fc = lane & 31;
  const uint2* __restrict__ G2 = (const uint2*)g;

  for (int grp = blockIdx.x; grp < nG; grp += gridDim.x) {
    int v = grp * 4 + wid;
    if (v >= N) continue;

    float4 a0 = make_float4(0.f, 0.f, 0.f, 0.f);
    float4 a1 = make_float4(0.f, 0.f, 0.f, 0.f);
    if (hf == 0) a0 = cvt4(G2[(size_t)v * 32 + fc]);   // self row

    int s0 = offs[v], s1 = offs[v + 1];
    int i = s0 + hf;
    for (; i + 6 < s1; i += 8) {
      int e0 = csr[i];
      int e1 = csr[i + 2];
      int e2 = csr[i + 4];
      int e3 = csr[i + 6];
      uint2 r0 = G2[(size_t)e0 * 32 + fc];
      uint2 r1 = G2[(size_t)e1 * 32 + fc];
      uint2 r2 = G2[(size_t)e2 * 32 + fc];
      uint2 r3 = G2[(size_t)e3 * 32 + fc];
      float4 f0 = cvt4(r0), f1 = cvt4(r1), f2 = cvt4(r2), f3 = cvt4(r3);
      a0.x += f0.x; a0.y += f0.y; a0.z += f0.z; a0.w += f0.w;
      a1.x += f1.x; a1.y += f1.y; a1.z += f1.z; a1.w += f1.w;
      a0.x += f2.x; a0.y += f2.y; a0.z += f2.z; a0.w += f2.w;
      a1.x += f3.x; a1.y += f3.y; a1.z += f3.z; a1.w += f3.w;
    }
    for (; i < s1; i += 2) {
      float4 f = cvt4(G2[(size_t)csr[i] * 32 + fc]);
      a0.x += f.x; a0.y += f.y; a0.z += f.z; a0.w += f.w;
    }
    a0.x += a1.x; a0.y += a1.y; a0.z += a1.z; a0.w += a1.w;

    a0.x += __shfl_xor(a0.x, 32, 64);
    a0.y += __shfl_xor(a0.y, 32, 64);
    a0.z += __shfl_xor(a0.z, 32, 64);
    a0.w += __shfl_xor(a0.w, 32, 64);

    float di = dinv[v];
    float4 bb = ((const float4*)bias)[fc];
    float4 o;
    o.x = fmaxf(fmaf(di, a0.x, bb.x), 0.f);
    o.y = fmaxf(fmaf(di, a0.y, bb.y), 0.f);
    o.z = fmaxf(fmaf(di, a0.z, bb.z), 0.f);
    o.w = fmaxf(fmaf(di, a0.w, bb.w), 0.f);

    if (FUSE_GEMV) {
      float4 w3v = ((const float4*)W3)[fc];
      float p = o.x * w3v.x + o.y * w3v.y + o.z * w3v.z + o.w * w3v.w;
      p += __shfl_xor(p, 1, 64);
      p += __shfl_xor(p, 2, 64);
      p += __shfl_xor(p, 4, 64);
      p += __shfl_xor(p, 8, 64);
      p += __shfl_xor(p, 16, 64);
      if (lane == 0) g3[v] = di * p;
    } else {
      if (hf == 0) ((float4*)tOut)[(size_t)v * 32 + fc] = o;
    }
  }
}

__device__ inline void agg3_phase(const float* __restrict__ g3, const int* __restrict__ offs,
                                  const int* __restrict__ csr, const float* __restrict__ dinv,
                                  const float* __restrict__ b3, float* __restrict__ out, int N) {
  int gid = blockIdx.x * 256 + threadIdx.x;
  int gsz = gridDim.x * 256;
  for (int v = gid; v < N; v += gsz) {
    float acc = g3[v];
    int i = offs[v], s1 = offs[v + 1];
    for (; i + 3 < s1; i += 4) {
      int e0 = csr[i], e1 = csr[i + 1], e2 = csr[i + 2], e3 = csr[i + 3];
      float r0 = g3[e0], r1 = g3[e1], r2 = g3[e2], r3 = g3[e3];
      acc += r0 + r1 + r2 + r3;
    }
    for (; i < s1; i++) acc += g3[csr[i]];
    out[v] = dinv[v] * acc + b3[0];
  }
}

// ---------------- mega compute kernel (cooperative, 1024 x 256) ----------------
__global__ __launch_bounds__(256, 4) void k_mega(
    const float* __restrict__ x, const _Float16* __restrict__ WtA,
    const _Float16* __restrict__ WtB, const float* __restrict__ W3,
    const float* __restrict__ b1, const float* __restrict__ b2,
    const float* __restrict__ b3, const float* __restrict__ dinv,
    const int* __restrict__ offs, const int* __restrict__ csr,
    __half* __restrict__ gH, float* __restrict__ tA, float* __restrict__ g3,
    float* __restrict__ out, int N) {
  cg::grid_group grid = cg::this_grid();
  __shared__ _Float16 Wl[128 * 128];   // 32 KB
  int nT = (N + 63) / 64;
  int nG = (N + 3) / 4;

  gemm_phase(x, WtA, dinv, gH, Wl, N, nT);            // layer 1 GEMM
  grid.sync();
  agg_phase<0>(gH, offs, csr, dinv, b1, nullptr, tA, nullptr, N, nG);   // agg1 + relu
  grid.sync();
  gemm_phase(tA, WtB, dinv, gH, Wl, N, nT);           // layer 2 GEMM
  grid.sync();
  agg_phase<1>(gH, offs, csr, dinv, b2, W3, nullptr, g3, N, nG);        // agg2 + relu + gemv3
  grid.sync();
  agg3_phase(g3, offs, csr, dinv, b3, out, N);        // layer 3 aggregate
}

extern "C" void kernel_launch(void* const* d_in, const int* in_sizes, int n_in,
                              void* d_out, int out_size, void* d_ws, size_t ws_size,
                              hipStream_t stream) {
  const float* x = (const float*)d_in[0];
  const int* ei = (const int*)d_in[1];
  const float* W1 = (const float*)d_in[2];
  const float* b1 = (const float*)d_in[3];
  const float* W2 = (const float*)d_in[4];
  const float* b2 = (const float*)d_in[5];
  const float* W3 = (const float*)d_in[6];
  const float* b3 = (const float*)d_in[7];
  float* out = (float*)d_out;

  int N = in_sizes[0] / 128;  // 50000
  int E = in_sizes[1] / 2;    // 800000

  char* base = (char*)d_ws;
  size_t off = 0;
  auto alloc = [&](size_t bytes) -> void* {
    void* p = base + off;
    off += (bytes + 255) & ~(size_t)255;
    return p;
  };
  int* cnt = (int*)alloc((size_t)N * 4);
  int* offs = (int*)alloc(((size_t)N + 1) * 4);
  int* cursor = (int*)alloc((size_t)N * 4);
  int* csr = (int*)alloc((size_t)E * 4);
  float* dinv = (float*)alloc((size_t)N * 4);
  int* gsum = (int*)alloc(4096 * 4);
  _Float16* WtA = (_Float16*)alloc(128 * 128 * 2);
  _Float16* WtB = (_Float16*)alloc(128 * 128 * 2);
  __half* gH = (__half*)alloc((size_t)N * 128 * 2);
  float* tA = (float*)alloc((size_t)N * 128 * 4);
  float* g3 = (float*)alloc((size_t)N * 4);
  (void)ws_size;

  int NB = (N + 255) / 256;   // 196

  void* a1[] = {(void*)&ei, (void*)&cnt, (void*)&offs, (void*)&cursor, (void*)&dinv,
                (void*)&gsum, (void*)&csr, (void*)&W1, (void*)&W2, (void*)&WtA,
                (void*)&WtB, (void*)&E, (void*)&N, (void*)&NB};
  (void)hipLaunchCooperativeKernel((const void*)k_csr, dim3(1024), dim3(256), a1, 0, stream);

  void* a2[] = {(void*)&x, (void*)&WtA, (void*)&WtB, (void*)&W3, (void*)&b1, (void*)&b2,
                (void*)&b3, (void*)&dinv, (void*)&offs, (void*)&csr, (void*)&gH,
                (void*)&tA, (void*)&g3, (void*)&out, (void*)&N};
  (void)hipLaunchCooperativeKernel((const void*)k_mega, dim3(1024), dim3(256), a2, 0, stream);
}